// Round 3
// baseline (329.841 us; speedup 1.0000x reference)
//
#include <hip/hip_runtime.h>
#include <stdint.h>

#define NN   2048
#define DD   128
#define DIN  256
#define ROWZ 75

typedef float f32x4 __attribute__((ext_vector_type(4)));
typedef short bf16x8 __attribute__((ext_vector_type(8)));
typedef unsigned int u32x4 __attribute__((ext_vector_type(4)));
typedef unsigned int u32x2 __attribute__((ext_vector_type(2)));
typedef unsigned long long u64x2 __attribute__((ext_vector_type(2)));

__device__ __forceinline__ unsigned short f2bf(float x){
  union { float f; unsigned int u; } v; v.f = x;
  unsigned int u = v.u;
  u += 0x7fffu + ((u >> 16) & 1u);   // RNE
  return (unsigned short)(u >> 16);
}
__device__ __forceinline__ float bf2f(unsigned short b){
  union { float f; unsigned int u; } v; v.u = ((unsigned int)b) << 16;
  return v.f;
}

// ---------------------------------------------------------------------------
// Kernel P: adj bit-pack, dedicated streaming kernel (unchanged from R5).
// 8 blocks/CU, 8 loads in flight/wave -> TLP-saturated streaming read.
// Layout: bit (m&63) of u64 word (m>>6) = (adj_eye[row][m] > 0).
// ---------------------------------------------------------------------------
__launch_bounds__(256, 8)
__global__ void pack_kernel(const int* __restrict__ adje,
                            unsigned long long* __restrict__ adjp)
{
  const int t  = threadIdx.x;
  const int wv = t >> 6;
  const int ln = t & 63;
#pragma unroll
  for (int rr = 0; rr < 2; ++rr){
    const int row = blockIdx.x * 8 + wv * 2 + rr;
    const int* arow = adje + (size_t)row * NN;
    unsigned long long* drow = adjp + (size_t)row * 32;
#pragma unroll
    for (int c = 0; c < 4; ++c){
      int pv[8];
#pragma unroll
      for (int j = 0; j < 8; ++j) pv[j] = arow[c*512 + j*64 + ln];
      unsigned long long m[8];
#pragma unroll
      for (int j = 0; j < 8; ++j) m[j] = __ballot(pv[j] > 0);
      if (ln == 0){
#pragma unroll
        for (int j = 0; j < 8; j += 2){
          u64x2 pk = { m[j], m[j+1] };
          *(u64x2*)(drow + c*8 + j) = pk;
        }
      }
    }
  }
}

// ---------------------------------------------------------------------------
// Kernel A: Wh = h @ W (fp32), row L2 norms.
// R6: register double-buffer on staging — tile kt+1's global loads issue
// before the FMA loop over tile kt (HBM latency hides under ~1000cy FMA).
// R5 serialized load->wait->ds_write->barrier each kt (full latency exposed).
// ---------------------------------------------------------------------------
__launch_bounds__(256, 2)
__global__ void wh_kernel(const float* __restrict__ h, const float* __restrict__ W,
                          unsigned short* __restrict__ whn, unsigned short* __restrict__ whT)
{
  __shared__ float hs[32][36];     // [k][row], pad 4: aligned + fewer bank conflicts
  __shared__ float Ws[32][128];
  __shared__ float ssp[32][33];
  __shared__ float sinv[32];

  const int t  = threadIdx.x;
  const int r0 = blockIdx.x * 32;        // global row base
  const int r4 = (t >> 5) * 4;           // row sub-base 0..28
  const int d4 = (t & 31) * 4;           // d sub-base 0..124

  float acc[4][4];
#pragma unroll
  for (int i = 0; i < 4; ++i)
#pragma unroll
    for (int j = 0; j < 4; ++j) acc[i][j] = 0.f;

  const int lrow = t >> 3;         // h stage: row 0..31
  const int lkb  = (t & 7) * 4;    // h stage: k sub-base
  const int wk   = t >> 3;         // W stage: k row 0..31
  const int wd   = (t & 7) * 16;   // W stage: d base

  // prefetch tile kt=0 into registers
  f32x4 ph = *(const f32x4*)(h + (size_t)(r0 + lrow) * DIN + lkb);
  f32x4 pW[4];
  {
    const float* ws = W + (size_t)wk * DD + wd;
#pragma unroll
    for (int e = 0; e < 4; ++e) pW[e] = ((const f32x4*)ws)[e];
  }

  for (int kt = 0; kt < 8; ++kt){
    __syncthreads();                       // prior tile's readers done
#pragma unroll
    for (int e = 0; e < 4; ++e) hs[lkb + e][lrow] = ph[e];
    {
      f32x4* dst = (f32x4*)&Ws[wk][wd];
#pragma unroll
      for (int e = 0; e < 4; ++e) dst[e] = pW[e];
    }
    __syncthreads();

    if (kt < 7){                           // issue next tile's loads now;
      ph = *(const f32x4*)(h + (size_t)(r0 + lrow) * DIN + (kt+1)*32 + lkb);
      const float* ws = W + (size_t)((kt+1)*32 + wk) * DD + wd;
#pragma unroll
      for (int e = 0; e < 4; ++e) pW[e] = ((const f32x4*)ws)[e];
    }                                      // ...they complete during the FMAs

#pragma unroll
    for (int k = 0; k < 32; ++k){
      f32x4 w4 = *(const f32x4*)&Ws[k][d4];
      f32x4 ha = *(const f32x4*)&hs[k][r4];
#pragma unroll
      for (int i = 0; i < 4; ++i)
#pragma unroll
        for (int j = 0; j < 4; ++j)
          acc[i][j] += ha[i] * w4[j];
    }
  }

  // row norms
#pragma unroll
  for (int i = 0; i < 4; ++i){
    float s = acc[i][0]*acc[i][0] + acc[i][1]*acc[i][1]
            + acc[i][2]*acc[i][2] + acc[i][3]*acc[i][3];
    ssp[r4 + i][t & 31] = s;
  }
  __syncthreads();
  if (t < 32){
    float ss = 0.f;
#pragma unroll
    for (int c = 0; c < 32; ++c) ss += ssp[t][c];
    sinv[t] = 1.0f / fmaxf(sqrtf(ss), 1e-12f);   // F.normalize eps semantics
  }
  __syncthreads();

  const int bb = r0 >> 11;
  const int n0 = (r0 & 2047) + r4;

  // whn: normalized bf16, row-major
#pragma unroll
  for (int i = 0; i < 4; ++i){
    const float inv = sinv[r4 + i];
    unsigned int lo = (unsigned int)f2bf(acc[i][0]*inv) | ((unsigned int)f2bf(acc[i][1]*inv) << 16);
    unsigned int hi = (unsigned int)f2bf(acc[i][2]*inv) | ((unsigned int)f2bf(acc[i][3]*inv) << 16);
    u32x2 pk = { lo, hi };
    *(u32x2*)(whn + (size_t)(r0 + r4 + i) * DD + d4) = pk;
  }
  // whT: unnormalized bf16, transposed [b][d][n] (8B store per d)
#pragma unroll
  for (int j = 0; j < 4; ++j){
    u32x2 pk;
#pragma unroll
    for (int e = 0; e < 2; ++e)
      pk[e] = (unsigned int)f2bf(acc[2*e][j]) | ((unsigned int)f2bf(acc[2*e + 1][j]) << 16);
    *(u32x2*)(whT + ((size_t)(bb * DD + d4 + j)) * NN + n0) = pk;
  }
}

// ---------------------------------------------------------------------------
// Kernel B: fused score -> mask -> softmax(no-max) -> PV -> ELU.
// R6 pipeline rework (T3/T4-style):
//  - Vt double-buffered (2x32KB). DMA for tile it+1 issues at the TOP of
//    iter it and stays in flight across both barriers. No vmcnt(0) drain in
//    the loop: raw s_barrier + sched_barrier(0) fences. Ordering proof:
//    vmcnt retires in issue order; the compiler's counted wait for kf(it)
//    (issued after DMA(it-1)) implies DMA(it-1) retired -> after barrier 1
//    every wave's share of buf_cur is complete.
//  - adj mask words prefetched 1 iter ahead in REGISTERS from global adjp
//    (quad-uniform, 8KB L1-resident) — frees the 8.5KB Ab LDS so the 74KB
//    double-buffered block still fits 2 blocks/CU.
//  - vf hoisted out of the s-loop (same fragment serves both s): Vt reads/2.
//  - s_setprio(1) around the PV MFMA cluster (T5).
// ---------------------------------------------------------------------------
__launch_bounds__(256, 2)
__global__ void attn_kernel(const unsigned short* __restrict__ whn,
                            const unsigned short* __restrict__ whT,
                            const unsigned int* __restrict__ adjp,
                            float* __restrict__ out)
{
  __shared__ unsigned short Vt[2][128 * 128];   // 64 KB: double-buffered V^T
  __shared__ unsigned short Pbuf[4][32 * 40];   // 10 KB: per-wave P (stride 40)
  __shared__ float linv_s[32];

  const int t    = threadIdx.x;
  const int w    = t >> 6;
  const int l    = t & 63;
  const int quad = l >> 4;
  const int l16  = l & 15;
  const int b     = blockIdx.x & 7;             // XCD-aligned batch
  const int qbase = (blockIdx.x >> 3) * 32;

  const unsigned short* whn_b = whn + (size_t)b * NN * DD;
  const unsigned short* whT_b = whT + (size_t)b * DD * NN;
  const unsigned int*   adjw  = adjp + ((size_t)(b * NN + qbase)) * 64;

  // Q fragments (A-layout: row = lane&15, k = quad*8 + j), held all loop
  bf16x8 qf[2][4];
#pragma unroll
  for (int s = 0; s < 2; ++s)
#pragma unroll
    for (int kc = 0; kc < 4; ++kc)
      qf[s][kc] = *(const bf16x8*)(whn_b + (size_t)(qbase + s*16 + l16) * DD + kc*32 + quad*8);

  f32x4 oacc[2][8];
  float lacc[2][4];
#pragma unroll
  for (int s = 0; s < 2; ++s){
#pragma unroll
    for (int dt = 0; dt < 8; ++dt) oacc[s][dt] = (f32x4){0.f, 0.f, 0.f, 0.f};
#pragma unroll
    for (int r = 0; r < 4; ++r) lacc[s][r] = 0.f;
  }

  unsigned short* const Pw = &Pbuf[w][0];

  // ---- prologue: DMA tile 0 into buf0; adj words for it=0 ----
#pragma unroll
  for (int ii = 0; ii < 8; ++ii){
    const int d   = w*32 + ii*4 + quad;
    const int gsw = l16 ^ (d & 7);
    const unsigned short* src = whT_b + (size_t)d * NN + gsw * 8;
    __builtin_amdgcn_global_load_lds(
        (const __attribute__((address_space(1))) void*)src,
        (__attribute__((address_space(3))) void*)&Vt[0][(w*32 + ii*4) * 128],
        16, 0, 0);
  }
  unsigned int aw[2][4];
#pragma unroll
  for (int s = 0; s < 2; ++s)
#pragma unroll
    for (int r = 0; r < 4; ++r)
      aw[s][r] = adjw[(size_t)(s*16 + quad*4 + r) * 64 + w];

  for (int it = 0; it < 16; ++it){
    const int m0  = it * 128;
    const int cur = it & 1;

    // ---- kf fragments, batched first (QK's counted wait covers these;
    //      in-order vmcnt retirement then implies DMA(it-1) done too) ----
    bf16x8 kf[2][4];
#pragma unroll
    for (int f = 0; f < 2; ++f)
#pragma unroll
      for (int kc = 0; kc < 4; ++kc)
        kf[f][kc] = *(const bf16x8*)(whn_b + (size_t)(m0 + w*32 + f*16 + l16) * DD + kc*32 + quad*8);

    // ---- adj words for it+1 + DMA tile it+1 into the other buffer ----
    unsigned int awn[2][4];
    if (it < 15){
#pragma unroll
      for (int s = 0; s < 2; ++s)
#pragma unroll
        for (int r = 0; r < 4; ++r)
          awn[s][r] = adjw[(size_t)(s*16 + quad*4 + r) * 64 + (it+1)*4 + w];
#pragma unroll
      for (int ii = 0; ii < 8; ++ii){
        const int d   = w*32 + ii*4 + quad;
        const int gsw = l16 ^ (d & 7);
        const unsigned short* src = whT_b + (size_t)d * NN + (m0 + 128) + gsw * 8;
        __builtin_amdgcn_global_load_lds(
            (const __attribute__((address_space(1))) void*)src,
            (__attribute__((address_space(3))) void*)&Vt[cur ^ 1][(w*32 + ii*4) * 128],
            16, 0, 0);
      }
    }

    // ---- QK + mask + exp -> P ----
#pragma unroll
    for (int f = 0; f < 2; ++f){
#pragma unroll
      for (int s = 0; s < 2; ++s){
        f32x4 sc = (f32x4){0.f, 0.f, 0.f, 0.f};
#pragma unroll
        for (int kc = 0; kc < 4; ++kc)
          sc = __builtin_amdgcn_mfma_f32_16x16x32_bf16(qf[s][kc], kf[f][kc], sc, 0, 0, 0);
#pragma unroll
        for (int r = 0; r < 4; ++r){
          const int qrow = qbase + s*16 + quad*4 + r;       // C row
          float sv = (qrow < ROWZ) ? 0.f : sc[r];           // row-zeroing bug emulation
          float p32 = ((aw[s][r] >> (f*16 + l16)) & 1u) ? __expf(sv) : 0.f;
          unsigned short pb = f2bf(p32);
          lacc[s][r] += bf2f(pb);
          Pw[(s*16 + quad*4 + r) * 40 + f*16 + l16] = pb;   // C-layout -> LDS
        }
      }
    }

    // ---- barrier 1: buf_cur complete everywhere (no vmcnt drain) ----
    __builtin_amdgcn_sched_barrier(0);
    __builtin_amdgcn_s_barrier();
    __builtin_amdgcn_sched_barrier(0);

    // ---- PV: out += P[16x32] * V[32x128]; vf shared across both s ----
    bf16x8 pfr0 = *(const bf16x8*)&Pw[(l16) * 40 + quad*8];
    bf16x8 pfr1 = *(const bf16x8*)&Pw[(16 + l16) * 40 + quad*8];
    __builtin_amdgcn_s_setprio(1);
#pragma unroll
    for (int dt = 0; dt < 8; ++dt){
      const int d  = dt*16 + l16;
      const int gg = (w*4 + quad) ^ (d & 7);
      bf16x8 vf = *(const bf16x8*)&Vt[cur][d * 128 + gg * 8];
      oacc[0][dt] = __builtin_amdgcn_mfma_f32_16x16x32_bf16(pfr0, vf, oacc[0][dt], 0, 0, 0);
      oacc[1][dt] = __builtin_amdgcn_mfma_f32_16x16x32_bf16(pfr1, vf, oacc[1][dt], 0, 0, 0);
    }
    __builtin_amdgcn_s_setprio(0);

    // ---- barrier 2: buf_nxt's readers (this PV ran on buf_cur; last iter's
    //      PV on buf_nxt finished before its barrier) — protects next DMA ----
    __builtin_amdgcn_sched_barrier(0);
    __builtin_amdgcn_s_barrier();
    __builtin_amdgcn_sched_barrier(0);

    if (it < 15){
#pragma unroll
      for (int s = 0; s < 2; ++s)
#pragma unroll
        for (int r = 0; r < 4; ++r)
          aw[s][r] = awn[s][r];
    }
  }

  // ---- l reduction (reuse own wave's Pbuf region as float scratch) ----
  {
    float* lredw = (float*)Pw;
#pragma unroll
    for (int s = 0; s < 2; ++s)
#pragma unroll
      for (int r = 0; r < 4; ++r)
        lredw[(s*16 + quad*4 + r) * 16 + l16] = lacc[s][r];
  }
  __syncthreads();   // full drain: loop DMA retired, Pbuf visible
  if (t < 32){
    float sum = 0.f;
    for (int ww = 0; ww < 4; ++ww){
      const float* lr = (const float*)&Pbuf[ww][0];
#pragma unroll
      for (int c = 0; c < 16; ++c) sum += lr[t * 16 + c];
    }
    linv_s[t] = 1.0f / sum;
  }

  // ---- output reduction across waves (reuse Vt[0] as 32KB float scratch) ----
  float* const ored = (float*)&Vt[0][0];
  for (int s = 0; s < 2; ++s){
    __syncthreads();   // linv visible / previous pass reads done
#pragma unroll
    for (int dt = 0; dt < 8; ++dt)
#pragma unroll
      for (int r = 0; r < 4; ++r)
        ored[w*2048 + (quad*4 + r)*128 + dt*16 + l16] = oacc[s][dt][r];
    __syncthreads();
#pragma unroll
    for (int j = 0; j < 8; ++j){
      const int o  = j*256 + t;
      const int ql = o >> 7, d = o & 127;
      float v = ored[ql*128 + d] + ored[2048 + ql*128 + d]
              + ored[4096 + ql*128 + d] + ored[6144 + ql*128 + d];
      v *= linv_s[s*16 + ql];
      v = (v > 0.f) ? v : expm1f(v);   // ELU (alpha=1)
      out[(size_t)(b*NN + qbase + s*16 + ql) * DD + d] = v;
    }
  }
}

extern "C" void kernel_launch(void* const* d_in, const int* in_sizes, int n_in,
                              void* d_out, int out_size, void* d_ws, size_t ws_size,
                              hipStream_t stream)
{
  const float* h       = (const float*)d_in[0];
  // d_in[1] = adj  (unused by the reference)
  const int*   adj_eye = (const int*)d_in[2];
  const float* W       = (const float*)d_in[3];
  float*       out     = (float*)d_out;

  unsigned short* whn  = (unsigned short*)d_ws;                   // 16384*128 bf16 = 4 MB
  unsigned short* whT  = whn + (size_t)16384 * 128;               // 8*128*2048 bf16 = 4 MB
  unsigned int*   adjp = (unsigned int*)(whT + (size_t)16384 * 128); // 16384*64 u32 = 4 MB

  pack_kernel<<<2048, 256, 0, stream>>>(adj_eye, (unsigned long long*)adjp);
  wh_kernel<<<512, 256, 0, stream>>>(h, W, whn, whT);
  attn_kernel<<<512, 256, 0, stream>>>(whn, whT, adjp, out);
}

// Round 4
// 285.848 us; speedup vs baseline: 1.1539x; 1.1539x over previous
//
#include <hip/hip_runtime.h>
#include <stdint.h>

#define NN   2048
#define DD   128
#define DIN  256
#define ROWZ 75

typedef float f32x4 __attribute__((ext_vector_type(4)));
typedef short bf16x8 __attribute__((ext_vector_type(8)));
typedef unsigned int u32x2 __attribute__((ext_vector_type(2)));

__device__ __forceinline__ unsigned short f2bf(float x){
  union { float f; unsigned int u; } v; v.f = x;
  unsigned int u = v.u;
  u += 0x7fffu + ((u >> 16) & 1u);   // RNE
  return (unsigned short)(u >> 16);
}
__device__ __forceinline__ float bf2f(unsigned short b){
  union { float f; unsigned int u; } v; v.u = ((unsigned int)b) << 16;
  return v.f;
}

// ---------------------------------------------------------------------------
// Kernel A: Wh = h @ W (fp32), row L2 norms.
// R7: batch = bid&7 so the XCD that WRITES batch b's whn/whT is the XCD that
// READS it in attn (round-robin dispatch: XCD = bid%8). Body = R6 (register
// double-buffered staging).
// ---------------------------------------------------------------------------
__launch_bounds__(256, 2)
__global__ void wh_kernel(const float* __restrict__ h, const float* __restrict__ W,
                          unsigned short* __restrict__ whn, unsigned short* __restrict__ whT)
{
  __shared__ float hs[32][36];
  __shared__ float Ws[32][128];
  __shared__ float ssp[32][33];
  __shared__ float sinv[32];

  const int t  = threadIdx.x;
  const int bid = blockIdx.x;
  const int r0 = ((bid & 7) << 11) | ((bid >> 3) << 5);   // batch=bid&7, row-group=bid>>3
  const int r4 = (t >> 5) * 4;
  const int d4 = (t & 31) * 4;

  float acc[4][4];
#pragma unroll
  for (int i = 0; i < 4; ++i)
#pragma unroll
    for (int j = 0; j < 4; ++j) acc[i][j] = 0.f;

  const int lrow = t >> 3;
  const int lkb  = (t & 7) * 4;
  const int wk   = t >> 3;
  const int wd   = (t & 7) * 16;

  f32x4 ph = *(const f32x4*)(h + (size_t)(r0 + lrow) * DIN + lkb);
  f32x4 pW[4];
  {
    const float* ws = W + (size_t)wk * DD + wd;
#pragma unroll
    for (int e = 0; e < 4; ++e) pW[e] = ((const f32x4*)ws)[e];
  }

  for (int kt = 0; kt < 8; ++kt){
    __syncthreads();
#pragma unroll
    for (int e = 0; e < 4; ++e) hs[lkb + e][lrow] = ph[e];
    {
      f32x4* dst = (f32x4*)&Ws[wk][wd];
#pragma unroll
      for (int e = 0; e < 4; ++e) dst[e] = pW[e];
    }
    __syncthreads();

    if (kt < 7){
      ph = *(const f32x4*)(h + (size_t)(r0 + lrow) * DIN + (kt+1)*32 + lkb);
      const float* ws = W + (size_t)((kt+1)*32 + wk) * DD + wd;
#pragma unroll
      for (int e = 0; e < 4; ++e) pW[e] = ((const f32x4*)ws)[e];
    }

#pragma unroll
    for (int k = 0; k < 32; ++k){
      f32x4 w4 = *(const f32x4*)&Ws[k][d4];
      f32x4 ha = *(const f32x4*)&hs[k][r4];
#pragma unroll
      for (int i = 0; i < 4; ++i)
#pragma unroll
        for (int j = 0; j < 4; ++j)
          acc[i][j] += ha[i] * w4[j];
    }
  }

#pragma unroll
  for (int i = 0; i < 4; ++i){
    float s = acc[i][0]*acc[i][0] + acc[i][1]*acc[i][1]
            + acc[i][2]*acc[i][2] + acc[i][3]*acc[i][3];
    ssp[r4 + i][t & 31] = s;
  }
  __syncthreads();
  if (t < 32){
    float ss = 0.f;
#pragma unroll
    for (int c = 0; c < 32; ++c) ss += ssp[t][c];
    sinv[t] = 1.0f / fmaxf(sqrtf(ss), 1e-12f);
  }
  __syncthreads();

  const int bb = r0 >> 11;
  const int n0 = (r0 & 2047) + r4;

#pragma unroll
  for (int i = 0; i < 4; ++i){
    const float inv = sinv[r4 + i];
    unsigned int lo = (unsigned int)f2bf(acc[i][0]*inv) | ((unsigned int)f2bf(acc[i][1]*inv) << 16);
    unsigned int hi = (unsigned int)f2bf(acc[i][2]*inv) | ((unsigned int)f2bf(acc[i][3]*inv) << 16);
    u32x2 pk = { lo, hi };
    *(u32x2*)(whn + (size_t)(r0 + r4 + i) * DD + d4) = pk;
  }
#pragma unroll
  for (int j = 0; j < 4; ++j){
    u32x2 pk;
#pragma unroll
    for (int e = 0; e < 2; ++e)
      pk[e] = (unsigned int)f2bf(acc[2*e][j]) | ((unsigned int)f2bf(acc[2*e + 1][j]) << 16);
    *(u32x2*)(whT + ((size_t)(bb * DD + d4 + j)) * NN + n0) = pk;
  }
}

// ---------------------------------------------------------------------------
// Kernel B (R7 rewrite): 256 blocks x 512 threads, 64 q-rows/block.
// Halves whn/whT cache traffic (512->256 MB) — the L3-BW bottleneck theory.
// 8 waves: qh = w>>2 (q-half), ms = w&3 (32-col m-strip). K AND V tiles both
// staged via global_load_lds (pre-swizzled source granules). adj read DIRECT
// from global (no pack kernel: zero reuse, packing saved nothing), register-
// prefetched 1 iter ahead. ONE barrier/iter: Pbuf is wave-private; the only
// cross-wave hazard (DMA completion) is covered by end-of-iter vmcnt(0)
// (issued a full iteration after the DMA -> ~retired) + raw s_barrier.
// ---------------------------------------------------------------------------
__launch_bounds__(512, 2)
__global__ void attn_kernel(const unsigned short* __restrict__ whn,
                            const unsigned short* __restrict__ whT,
                            const int* __restrict__ adje,
                            float* __restrict__ out)
{
  __shared__ unsigned short Kt[2][128 * 128];   // 64 KB K-tile (rows = m, cols = d)
  __shared__ unsigned short Vt[2][128 * 128];   // 64 KB V-tile (rows = d, cols = n)
  __shared__ unsigned short Pbuf[8][32 * 40];   // 20 KB per-wave P
  __shared__ float linv_s[64];

  const int t    = threadIdx.x;
  const int w    = t >> 6;
  const int l    = t & 63;
  const int quad = l >> 4;
  const int l16  = l & 15;
  const int qh   = w >> 2;            // q-half 0/1
  const int ms   = w & 3;             // m-strip 0..3
  const int b     = blockIdx.x & 7;   // XCD-pinned batch (round-robin dispatch)
  const int qbase = (blockIdx.x >> 3) * 64;

  const unsigned short* whn_b = whn + (size_t)b * NN * DD;
  const unsigned short* whT_b = whT + (size_t)b * DD * NN;
  const int*            adj_b = adje + (size_t)b * NN * NN;

  // stage K+V tile for m0 into buffer cc (8 instrs/wave; src pre-swizzled)
#define STAGE(M0, CC)                                                          \
  if (w < 4){                                                                  \
    _Pragma("unroll")                                                          \
    for (int ii = 0; ii < 8; ++ii){                                            \
      const int row = w*32 + ii*4 + (l >> 4);                                  \
      const unsigned short* src = whn_b + (size_t)((M0) + row) * DD            \
                                  + (l16 ^ (row & 7)) * 8;                     \
      __builtin_amdgcn_global_load_lds(                                        \
          (const __attribute__((address_space(1))) void*)src,                  \
          (__attribute__((address_space(3))) void*)&Kt[CC][(w*32 + ii*4)*128], \
          16, 0, 0);                                                           \
    }                                                                          \
  } else {                                                                     \
    _Pragma("unroll")                                                          \
    for (int ii = 0; ii < 8; ++ii){                                            \
      const int dv = (w-4)*32 + ii*4 + (l >> 4);                               \
      const unsigned short* src = whT_b + (size_t)dv * NN + (M0)               \
                                  + (l16 ^ (dv & 7)) * 8;                      \
      __builtin_amdgcn_global_load_lds(                                        \
          (const __attribute__((address_space(1))) void*)src,                  \
          (__attribute__((address_space(3))) void*)&Vt[CC][((w-4)*32+ii*4)*128],\
          16, 0, 0);                                                           \
    }                                                                          \
  }

  // Q fragments: rows qbase + qh*32 + s*16 + l16
  bf16x8 qf[2][4];
#pragma unroll
  for (int s = 0; s < 2; ++s)
#pragma unroll
    for (int kc = 0; kc < 4; ++kc)
      qf[s][kc] = *(const bf16x8*)(whn_b + (size_t)(qbase + qh*32 + s*16 + l16) * DD + kc*32 + quad*8);

  f32x4 oacc[2][8];
  float lacc[2][4];
#pragma unroll
  for (int s = 0; s < 2; ++s){
#pragma unroll
    for (int dt = 0; dt < 8; ++dt) oacc[s][dt] = (f32x4){0.f, 0.f, 0.f, 0.f};
#pragma unroll
    for (int r = 0; r < 4; ++r) lacc[s][r] = 0.f;
  }

  unsigned short* const Pw = &Pbuf[w][0];

  // ---- prologue: adj(0) + tiles(0) ----
  int av[2][2][4];
#pragma unroll
  for (int f = 0; f < 2; ++f)
#pragma unroll
    for (int s = 0; s < 2; ++s)
#pragma unroll
      for (int r = 0; r < 4; ++r)
        av[f][s][r] = adj_b[(size_t)(qbase + qh*32 + s*16 + quad*4 + r) * NN + ms*32 + f*16 + l16];
  STAGE(0, 0)
  __syncthreads();   // drains prologue DMA; all waves aligned

  for (int it = 0; it < 16; ++it){
    const int m0  = it * 128;
    const int cur = it & 1;

    // ---- prefetch it+1: adj ints -> regs, K/V tiles -> other LDS buffer ----
    int avn[2][2][4];
    if (it < 15){
      const int mn = m0 + 128;
#pragma unroll
      for (int f = 0; f < 2; ++f)
#pragma unroll
        for (int s = 0; s < 2; ++s)
#pragma unroll
          for (int r = 0; r < 4; ++r)
            avn[f][s][r] = adj_b[(size_t)(qbase + qh*32 + s*16 + quad*4 + r) * NN + mn + ms*32 + f*16 + l16];
      STAGE(mn, cur ^ 1)
    }

    // ---- QK from LDS K-tile + mask + exp -> P (wave-private) ----
    bf16x8 kf[2][4];
#pragma unroll
    for (int f = 0; f < 2; ++f)
#pragma unroll
      for (int kc = 0; kc < 4; ++kc){
        const int row = ms*32 + f*16 + l16;
        kf[f][kc] = *(const bf16x8*)&Kt[cur][row*128 + (((kc*4 + quad) ^ (l16 & 7)) * 8)];
      }
#pragma unroll
    for (int f = 0; f < 2; ++f){
#pragma unroll
      for (int s = 0; s < 2; ++s){
        f32x4 sc = (f32x4){0.f, 0.f, 0.f, 0.f};
#pragma unroll
        for (int kc = 0; kc < 4; ++kc)
          sc = __builtin_amdgcn_mfma_f32_16x16x32_bf16(qf[s][kc], kf[f][kc], sc, 0, 0, 0);
#pragma unroll
        for (int r = 0; r < 4; ++r){
          const int qrow = qbase + qh*32 + s*16 + quad*4 + r;
          float sv = (qrow < ROWZ) ? 0.f : sc[r];           // row-zeroing bug emulation
          float p32 = (av[f][s][r] > 0) ? __expf(sv) : 0.f;
          unsigned short pb = f2bf(p32);
          lacc[s][r] += bf2f(pb);
          Pw[(s*16 + quad*4 + r) * 40 + f*16 + l16] = pb;
        }
      }
    }

    // ---- PV: P(32q x 32m) * V(32m x 128d), vf shared across both q-subtiles ----
    bf16x8 pfr0 = *(const bf16x8*)&Pw[(l16) * 40 + quad*8];
    bf16x8 pfr1 = *(const bf16x8*)&Pw[(16 + l16) * 40 + quad*8];
    __builtin_amdgcn_s_setprio(1);
#pragma unroll
    for (int dt = 0; dt < 8; ++dt){
      const int d = dt*16 + l16;
      bf16x8 vf = *(const bf16x8*)&Vt[cur][d*128 + (((ms*4 + quad) ^ (l16 & 7)) * 8)];
      oacc[0][dt] = __builtin_amdgcn_mfma_f32_16x16x32_bf16(pfr0, vf, oacc[0][dt], 0, 0, 0);
      oacc[1][dt] = __builtin_amdgcn_mfma_f32_16x16x32_bf16(pfr1, vf, oacc[1][dt], 0, 0, 0);
    }
    __builtin_amdgcn_s_setprio(0);

    // ---- single barrier: DMA(it+1) had the whole iter in flight -> vmcnt(0)
    //      is ~free; barrier then publishes both LDS buffers' state ----
    __builtin_amdgcn_sched_barrier(0);
    asm volatile("s_waitcnt vmcnt(0)" ::: "memory");
    __builtin_amdgcn_sched_barrier(0);
    __builtin_amdgcn_s_barrier();
    __builtin_amdgcn_sched_barrier(0);

    if (it < 15){
#pragma unroll
      for (int f = 0; f < 2; ++f)
#pragma unroll
        for (int s = 0; s < 2; ++s)
#pragma unroll
          for (int r = 0; r < 4; ++r)
            av[f][s][r] = avn[f][s][r];
    }
  }

  // ---- l reduction: lred[qrow64][ms*16+l16] in Pbuf scratch (16 KB) ----
  {
    float* fl = (float*)&Pbuf[0][0];
#pragma unroll
    for (int s = 0; s < 2; ++s)
#pragma unroll
      for (int r = 0; r < 4; ++r)
        fl[(qh*32 + s*16 + quad*4 + r) * 64 + ms*16 + l16] = lacc[s][r];
  }
  __syncthreads();
  if (t < 64){
    const float* fl = (const float*)&Pbuf[0][0];
    float sum = 0.f;
#pragma unroll
    for (int c = 0; c < 64; ++c) sum += fl[t * 64 + c];
    linv_s[t] = 1.0f / sum;
  }

  // ---- output: reduce oacc across the 4 m-strips per q-half (Kt as scratch) ----
  float* const owf = (float*)&Kt[0][0];    // 64 KB: [wave][16 rows][128 d]
  for (int s = 0; s < 2; ++s){
    __syncthreads();
#pragma unroll
    for (int dt = 0; dt < 8; ++dt)
#pragma unroll
      for (int r = 0; r < 4; ++r)
        owf[w*2048 + (quad*4 + r)*128 + dt*16 + l16] = oacc[s][dt][r];
    __syncthreads();
#pragma unroll
    for (int j = 0; j < 8; ++j){
      const int o     = j*512 + t;          // 4096 = 32 rows x 128 d
      const int row32 = o >> 7;
      const int d     = o & 127;
      const int qh2   = row32 >> 4;
      const int r16   = row32 & 15;
      float v = owf[(qh2*4 + 0)*2048 + r16*128 + d]
              + owf[(qh2*4 + 1)*2048 + r16*128 + d]
              + owf[(qh2*4 + 2)*2048 + r16*128 + d]
              + owf[(qh2*4 + 3)*2048 + r16*128 + d];
      const int qrl = qh2*32 + s*16 + r16;
      v *= linv_s[qrl];
      v = (v > 0.f) ? v : expm1f(v);        // ELU (alpha=1)
      out[(size_t)(b*NN + qbase + qrl) * DD + d] = v;
    }
  }
#undef STAGE
}

extern "C" void kernel_launch(void* const* d_in, const int* in_sizes, int n_in,
                              void* d_out, int out_size, void* d_ws, size_t ws_size,
                              hipStream_t stream)
{
  const float* h       = (const float*)d_in[0];
  // d_in[1] = adj  (unused by the reference)
  const int*   adj_eye = (const int*)d_in[2];
  const float* W       = (const float*)d_in[3];
  float*       out     = (float*)d_out;

  unsigned short* whn  = (unsigned short*)d_ws;                   // 16384*128 bf16 = 4 MB
  unsigned short* whT  = whn + (size_t)16384 * 128;               // 8*128*2048 bf16 = 4 MB

  wh_kernel<<<512, 256, 0, stream>>>(h, W, whn, whT);
  attn_kernel<<<256, 512, 0, stream>>>(whn, whT, adj_eye, out);
}